// Round 11
// baseline (230.182 us; speedup 1.0000x reference)
//
#include <hip/hip_runtime.h>

#define S_LEN 2048
#define D_MODEL 1024
#define NH 16
#define DH 64

typedef __bf16 bf16x8 __attribute__((ext_vector_type(8)));
typedef __bf16 bf16x4 __attribute__((ext_vector_type(4)));
typedef float f32x4 __attribute__((ext_vector_type(4)));

__device__ __forceinline__ unsigned short f2bf(float f) {
  unsigned int x = __float_as_uint(f);
  x += 0x7fffu + ((x >> 16) & 1u);  // RNE
  return (unsigned short)(x >> 16);
}

__device__ __forceinline__ bf16x4 cvt4(f32x4 v) {
  return __builtin_convertvector(v, bf16x4);
}

__device__ __forceinline__ float exp2raw(float x) {
#if __has_builtin(__builtin_amdgcn_exp2f)
  return __builtin_amdgcn_exp2f(x);
#else
  return exp2f(x);
#endif
}

__device__ __forceinline__ f32x4 mfma16(bf16x8 a, bf16x8 b, f32x4 c) {
  return __builtin_amdgcn_mfma_f32_16x16x32_bf16(a, b, c, 0, 0, 0);
}

__device__ __forceinline__ void gl2lds(const unsigned short* g, unsigned short* l) {
  __builtin_amdgcn_global_load_lds(
      (__attribute__((address_space(1))) void*)g,
      (__attribute__((address_space(3))) void*)l, 16, 0, 0);
}

// ---- fused prep: pack mask bits (blocks 0..32767) + fp32->bf16 convert ----
__global__ __launch_bounds__(256) void prep_kernel(
    const float* __restrict__ q, const float* __restrict__ wq,
    const float* __restrict__ wk, const float* __restrict__ wv,
    const float* __restrict__ wo, const int* __restrict__ mask,
    unsigned short* __restrict__ qbf, unsigned short* __restrict__ wbf,
    unsigned long long* __restrict__ bits) {
  const int bx = blockIdx.x;
  if (bx < 32768) {  // pack mask: 1 bit per (b,q,key), lane i <-> bit i
    int i = bx * 256 + threadIdx.x;
    unsigned long long bal = __ballot(mask[i] != 0);
    if ((threadIdx.x & 63) == 0) bits[i >> 6] = bal;
  } else {  // convert 8 floats per thread
    const long t = (long)(bx - 32768) * 256 + threadIdx.x;
    const float* src;
    unsigned short* dst;
    long e;
    if (t < 524288) { src = q; dst = qbf; e = t * 8; }
    else {
      long u = t - 524288;
      int wi = (int)(u >> 17);
      e = (u & 131071) * 8;
      src = wi == 0 ? wq : wi == 1 ? wk : wi == 2 ? wv : wo;
      dst = wbf + (long)wi * 1048576;
    }
    float4 a = *(const float4*)(src + e);
    float4 b = *(const float4*)(src + e + 4);
    ushort4 p0 = {f2bf(a.x), f2bf(a.y), f2bf(a.z), f2bf(a.w)};
    ushort4 p1 = {f2bf(b.x), f2bf(b.y), f2bf(b.z), f2bf(b.w)};
    *(ushort4*)(dst + e) = p0;
    *(ushort4*)(dst + e + 4) = p1;
  }
}

// ---- fused QKV: C = A(4096x1024) @ [Wq;Wk;Wv](3072x1024)^T ----
// BK=32, glds DOUBLE-BUFFER, ONE barrier/iter: loads issued right after the
// barrier land during compute; next barrier drains warm loads (no cold stall).
// wi<2 (Q,K): swapped operands -> C^T -> packed b64 stores. wi==2: V^T.
__global__ __launch_bounds__(256) void gemm_qkv(
    const unsigned short* __restrict__ A, const unsigned short* __restrict__ W3,
    unsigned short* __restrict__ qb, unsigned short* __restrict__ kb,
    unsigned short* __restrict__ vt, float qscale) {
  __shared__ unsigned short As[2][128 * 32];  // 16 KB
  __shared__ unsigned short Bs[2][128 * 32];  // 16 KB
  const int tid = threadIdx.x, lane = tid & 63, wid = tid >> 6;
  const int wm = wid >> 1, wn = wid & 1;
  const int quad = lane >> 4, c = lane & 15;
  const int nG = blockIdx.x * 128;
  const int wi = nG >> 10, nn0 = nG & 1023;
  const int m0 = blockIdx.y * 128;
  const int srow = lane >> 2, sc4 = (lane & 3) * 8;
  const unsigned short* ag = A + (size_t)(m0 + wid * 32 + srow) * 1024 + sc4;
  const unsigned short* bg =
      W3 + (size_t)wi * 1048576 + (size_t)(nn0 + wid * 32 + srow) * 1024 + sc4;
  f32x4 acc[4][4] = {};
  // prologue: tile 0 -> buf 0
  gl2lds(ag, &As[0][(wid * 32) * 32]);
  gl2lds(ag + 16 * 1024, &As[0][(wid * 32 + 16) * 32]);
  gl2lds(bg, &Bs[0][(wid * 32) * 32]);
  gl2lds(bg + 16 * 1024, &Bs[0][(wid * 32 + 16) * 32]);
  if (wi < 2) {  // ---- swapped-operand path (Q, K) ----
    for (int kk = 0; kk < 1024; kk += 32) {
      const int pb = (kk >> 5) & 1;
      __syncthreads();  // drains glds(->pb) issued last iter (warm)
      if (kk + 32 < 1024) {
        gl2lds(ag + kk + 32, &As[pb ^ 1][(wid * 32) * 32]);
        gl2lds(ag + 16 * 1024 + kk + 32, &As[pb ^ 1][(wid * 32 + 16) * 32]);
        gl2lds(bg + kk + 32, &Bs[pb ^ 1][(wid * 32) * 32]);
        gl2lds(bg + 16 * 1024 + kk + 32, &Bs[pb ^ 1][(wid * 32 + 16) * 32]);
      }
      bf16x8 a[4], b[4];
#pragma unroll
      for (int mt = 0; mt < 4; ++mt)
        a[mt] = *(const bf16x8*)(&As[pb][(wm * 64 + mt * 16 + c) * 32 + quad * 8]);
#pragma unroll
      for (int nt = 0; nt < 4; ++nt)
        b[nt] = *(const bf16x8*)(&Bs[pb][(wn * 64 + nt * 16 + c) * 32 + quad * 8]);
#pragma unroll
      for (int mt = 0; mt < 4; ++mt)
#pragma unroll
        for (int nt = 0; nt < 4; ++nt)
          acc[mt][nt] = mfma16(b[nt], a[mt], acc[mt][nt]);  // swapped
    }
    unsigned short* dst = (wi == 0) ? qb : kb;
    const float sc = (wi == 0) ? qscale : 1.0f;
#pragma unroll
    for (int mt = 0; mt < 4; ++mt) {
#pragma unroll
      for (int nt = 0; nt < 4; ++nt) {
        const int ss = m0 + wm * 64 + mt * 16 + c;          // s (c-side)
        const int nS = nn0 + wn * 64 + nt * 16 + quad * 4;  // n (quad-side)
        const int hh = nS >> 6, d0 = nS & 63;
        const int bb = ss >> 11, sl = ss & 2047;
        f32x4 v = acc[mt][nt] * sc;
        *(bf16x4*)(dst + (size_t)((bb * NH + hh) * S_LEN + sl) * DH + d0) =
            cvt4(v);
      }
    }
  } else {  // ---- original orientation (V -> V^T) ----
    for (int kk = 0; kk < 1024; kk += 32) {
      const int pb = (kk >> 5) & 1;
      __syncthreads();
      if (kk + 32 < 1024) {
        gl2lds(ag + kk + 32, &As[pb ^ 1][(wid * 32) * 32]);
        gl2lds(ag + 16 * 1024 + kk + 32, &As[pb ^ 1][(wid * 32 + 16) * 32]);
        gl2lds(bg + kk + 32, &Bs[pb ^ 1][(wid * 32) * 32]);
        gl2lds(bg + 16 * 1024 + kk + 32, &Bs[pb ^ 1][(wid * 32 + 16) * 32]);
      }
      bf16x8 a[4], b[4];
#pragma unroll
      for (int mt = 0; mt < 4; ++mt)
        a[mt] = *(const bf16x8*)(&As[pb][(wm * 64 + mt * 16 + c) * 32 + quad * 8]);
#pragma unroll
      for (int nt = 0; nt < 4; ++nt)
        b[nt] = *(const bf16x8*)(&Bs[pb][(wn * 64 + nt * 16 + c) * 32 + quad * 8]);
#pragma unroll
      for (int mt = 0; mt < 4; ++mt)
#pragma unroll
        for (int nt = 0; nt < 4; ++nt)
          acc[mt][nt] = mfma16(a[mt], b[nt], acc[mt][nt]);
    }
#pragma unroll
    for (int mt = 0; mt < 4; ++mt) {
#pragma unroll
      for (int nt = 0; nt < 4; ++nt) {
        const int mb = m0 + wm * 64 + mt * 16 + quad * 4;
        const int n = nn0 + wn * 64 + nt * 16 + c;
        const int hh = n >> 6, d = n & 63;
        const int bb = mb >> 11, ss = mb & 2047;
        *(bf16x4*)(vt + (size_t)((bb * NH + hh) * DH + d) * S_LEN + ss) =
            cvt4(acc[mt][nt]);
      }
    }
  }
}

// ---- O projection: BK=32 glds double-buffer, swapped -> float4 stores ----
__global__ __launch_bounds__(256) void gemm_out(
    const unsigned short* __restrict__ A, const unsigned short* __restrict__ W,
    float* __restrict__ out, const float* __restrict__ bias) {
  __shared__ unsigned short As[2][128 * 32];  // 16 KB
  __shared__ unsigned short Bs[2][64 * 32];   // 8 KB
  const int tid = threadIdx.x, lane = tid & 63, wid = tid >> 6;
  const int wm = wid >> 1, wn = wid & 1;
  const int quad = lane >> 4, c = lane & 15;
  const int n0 = blockIdx.x * 64, m0 = blockIdx.y * 128;
  const int srow = lane >> 2, sc4 = (lane & 3) * 8;
  const unsigned short* ag = A + (size_t)(m0 + wid * 32 + srow) * 1024 + sc4;
  const unsigned short* bg = W + (size_t)(n0 + wid * 16 + srow) * 1024 + sc4;
  f32x4 acc[4][2] = {};
  gl2lds(ag, &As[0][(wid * 32) * 32]);
  gl2lds(ag + 16 * 1024, &As[0][(wid * 32 + 16) * 32]);
  gl2lds(bg, &Bs[0][(wid * 16) * 32]);
  for (int kk = 0; kk < 1024; kk += 32) {
    const int pb = (kk >> 5) & 1;
    __syncthreads();
    if (kk + 32 < 1024) {
      gl2lds(ag + kk + 32, &As[pb ^ 1][(wid * 32) * 32]);
      gl2lds(ag + 16 * 1024 + kk + 32, &As[pb ^ 1][(wid * 32 + 16) * 32]);
      gl2lds(bg + kk + 32, &Bs[pb ^ 1][(wid * 16) * 32]);
    }
    bf16x8 a[4], b[2];
#pragma unroll
    for (int mt = 0; mt < 4; ++mt)
      a[mt] = *(const bf16x8*)(&As[pb][(wm * 64 + mt * 16 + c) * 32 + quad * 8]);
#pragma unroll
    for (int nt = 0; nt < 2; ++nt)
      b[nt] = *(const bf16x8*)(&Bs[pb][(wn * 32 + nt * 16 + c) * 32 + quad * 8]);
#pragma unroll
    for (int mt = 0; mt < 4; ++mt)
#pragma unroll
      for (int nt = 0; nt < 2; ++nt)
        acc[mt][nt] = mfma16(b[nt], a[mt], acc[mt][nt]);  // swapped
  }
#pragma unroll
  for (int mt = 0; mt < 4; ++mt) {
#pragma unroll
    for (int nt = 0; nt < 2; ++nt) {
      const int m = m0 + wm * 64 + mt * 16 + c;         // m (c-side)
      const int n = n0 + wn * 32 + nt * 16 + quad * 4;  // n (quad-side)
      f32x4 bv = *(const f32x4*)(bias + n);
      f32x4 r = acc[mt][nt] + bv;
      *(f32x4*)(out + (size_t)m * D_MODEL + n) = r;
    }
  }
}

// ---- flash attention: barrier-free K-loop + REGISTER MASK PREFETCH ----
// Mask words for tile t+1 are loaded into regs during tile t (issued with
// the K-restage; FIFO: top vmcnt(8) drains K, pre-PV vmcnt(8) drains V+masks)
// so the softmax phase has zero exposed global latency.
__global__ __launch_bounds__(256, 2) void attn_kernel(
    const unsigned short* __restrict__ qb, const unsigned short* __restrict__ kb,
    const unsigned short* __restrict__ vt,
    const unsigned long long* __restrict__ mbits,
    unsigned short* __restrict__ ctx) {
  const int h = blockIdx.x, qt = blockIdx.y, b = blockIdx.z;
  const int bh = b * NH + h;
  const int tid = threadIdx.x, lane = tid & 63, wid = tid >> 6;
  const int quad = lane >> 4, c = lane & 15, cx = c & 7;
  const int qw = wid & 1, kh = wid >> 1;
  const int q0 = qt * 128;
  __shared__ __align__(16) unsigned short KVw[4][8192];   // 64 KB: per-wave K|V
  __shared__ __align__(16) unsigned short Pbuf[4][16 * 72];  // 9 KB

  const int qbase = q0 + qw * 64;
  const unsigned short* qp = qb + (size_t)(bh * S_LEN + qbase + c) * DH;
  bf16x8 bq[4][2];
#pragma unroll
  for (int sub = 0; sub < 4; ++sub) {
    bq[sub][0] = *(const bf16x8*)(qp + sub * 16 * DH + quad * 8);
    bq[sub][1] = *(const bf16x8*)(qp + sub * 16 * DH + 32 + quad * 8);
  }

  f32x4 o[4][4] = {};
  float lacc[4] = {0.f, 0.f, 0.f, 0.f};
  const unsigned long long* mq0 =
      mbits + (size_t)(b * S_LEN + qbase + c) * 32 + kh * 16;

  // mask prefetch for tile 0 (issued before the K/V glds)
  unsigned long long mw[4];
#pragma unroll
  for (int sub = 0; sub < 4; ++sub) mw[sub] = mq0[sub * 512];

  const int srow = lane >> 3;
  const int schk = ((lane & 7) ^ srow) * 8;  // XOR-swizzled 16B chunk
  unsigned short* Kw = KVw[wid];
  unsigned short* Vw = KVw[wid] + 4096;
  unsigned short* Pw = Pbuf[wid];

  const unsigned short* gK =
      kb + (size_t)(bh * S_LEN + kh * 1024 + srow) * DH + schk;
  const unsigned short* gV =
      vt + (size_t)(bh * DH + srow) * S_LEN + kh * 1024 + schk;

  // prologue: all K, then all V (FIFO: bq8, m4, K8, V8)
#pragma unroll
  for (int i = 0; i < 8; ++i) gl2lds(gK + (size_t)(i * 8) * DH, &Kw[i * 512]);
#pragma unroll
  for (int i = 0; i < 8; ++i)
    gl2lds(gV + (size_t)(i * 8) * S_LEN, &Vw[i * 512]);

  for (int kt = 0; kt < 1024; kt += 64) {
    // drain through K(t); V(t) (8 newest) may stay in flight
    asm volatile("s_waitcnt vmcnt(8)" ::: "memory");

    bf16x8 kf[8];
#pragma unroll
    for (int g = 0; g < 4; ++g) {
      const int rho = g * 16 + c;
      kf[2 * g] = *(const bf16x8*)(&Kw[rho * 64 + (quad ^ cx) * 8]);
      kf[2 * g + 1] = *(const bf16x8*)(&Kw[rho * 64 + ((4 + quad) ^ cx) * 8]);
    }
    asm volatile("s_waitcnt lgkmcnt(0)" ::: "memory");  // kf in regs

    // prefetch tile t+1: masks (regs) + K restage (in flight across softmax/PV)
    unsigned long long mwn[4];
    if (kt + 64 < 1024) {
      const int min = (kt >> 6) + 1;
#pragma unroll
      for (int sub = 0; sub < 4; ++sub) mwn[sub] = mq0[sub * 512 + min];
#pragma unroll
      for (int i = 0; i < 8; ++i)
        gl2lds(gK + (size_t)(kt + 64 + i * 8) * DH, &Kw[i * 512]);
    }

    bf16x8 bp[4][2];
#pragma unroll
    for (int sub = 0; sub < 4; ++sub) {
      f32x4 s[4];
#pragma unroll
      for (int g = 0; g < 4; ++g) {
        f32x4 z = {};
        z = mfma16(kf[2 * g], bq[sub][0], z);
        z = mfma16(kf[2 * g + 1], bq[sub][1], z);
        s[g] = z;
      }
      const unsigned int wlo = (unsigned int)mw[sub];
      const unsigned int whi = (unsigned int)(mw[sub] >> 32);
      float lp = 0.f;
#pragma unroll
      for (int g = 0; g < 4; ++g) {
        const unsigned int bits =
            ((g & 2) ? whi : wlo) >> ((g & 1) * 16 + quad * 4);
        f32x4 p;
#pragma unroll
        for (int r = 0; r < 4; ++r) {
          const float e = exp2raw(s[g][r]);
          p[r] = ((bits >> r) & 1u) ? 0.f : e;
          lp += p[r];
        }
        *(bf16x4*)(&Pw[c * 72 + g * 16 + quad * 4]) = cvt4(p);
      }
      lacc[sub] += lp;
      bp[sub][0] = *(const bf16x8*)(&Pw[c * 72 + quad * 8]);
      bp[sub][1] = *(const bf16x8*)(&Pw[c * 72 + 32 + quad * 8]);
    }

    if (kt + 64 < 1024) {
      // outstanding: V8(t), m4(t+1), K8(t+1) -> drain 12 oldest = V + masks
      asm volatile("s_waitcnt vmcnt(8)" ::: "memory");
#pragma unroll
      for (int sub = 0; sub < 4; ++sub) mw[sub] = mwn[sub];
    } else {
      asm volatile("s_waitcnt vmcnt(0)" ::: "memory");
    }

#pragma unroll
    for (int ks = 0; ks < 2; ++ks) {
#pragma unroll
      for (int nt = 0; nt < 4; ++nt) {
        bf16x8 av = *(const bf16x8*)(
            &Vw[(nt * 16 + c) * 64 + ((ks * 4 + quad) ^ cx) * 8]);
#pragma unroll
        for (int sub = 0; sub < 4; ++sub)
          o[sub][nt] = mfma16(av, bp[sub][ks], o[sub][nt]);
      }
    }
    asm volatile("s_waitcnt lgkmcnt(0)" ::: "memory");  // Vw WAR
    if (kt + 64 < 1024) {
#pragma unroll
      for (int i = 0; i < 8; ++i)
        gl2lds(gV + (size_t)(i * 8) * S_LEN + kt + 64, &Vw[i * 512]);
    }
  }

#pragma unroll
  for (int sub = 0; sub < 4; ++sub) {
    lacc[sub] += __shfl_xor(lacc[sub], 16, 64);
    lacc[sub] += __shfl_xor(lacc[sub], 32, 64);
  }

  __syncthreads();  // all waves done with KVw before merge reuse
  float* mrg = (float*)&KVw[0][0];
  float* ml = mrg + 8 * 1088;
  if (kh == 1) {
#pragma unroll
    for (int sub = 0; sub < 4; ++sub) {
      float* mo = mrg + (qw * 4 + sub) * 1088;
#pragma unroll
      for (int nt = 0; nt < 4; ++nt)
        *(f32x4*)(mo + c * 68 + nt * 16 + quad * 4) = o[sub][nt];
      if (quad == 0) ml[(qw * 4 + sub) * 16 + c] = lacc[sub];
    }
  }
  __syncthreads();
  if (kh == 0) {
#pragma unroll
    for (int sub = 0; sub < 4; ++sub) {
      const int pp = qw * 4 + sub;
      const float inv = 1.0f / (lacc[sub] + ml[pp * 16 + c]);
      const int q = qbase + sub * 16 + c;
      const float* mo = mrg + pp * 1088;
#pragma unroll
      for (int nt = 0; nt < 4; ++nt) {
        f32x4 ob = *(const f32x4*)(mo + c * 68 + nt * 16 + quad * 4);
        f32x4 rr = (o[sub][nt] + ob) * inv;
        *(bf16x4*)(ctx + (size_t)(b * S_LEN + q) * D_MODEL + h * DH + nt * 16 +
                   quad * 4) = cvt4(rr);
      }
    }
  }
}

extern "C" void kernel_launch(void* const* d_in, const int* in_sizes, int n_in,
                              void* d_out, int out_size, void* d_ws, size_t ws_size,
                              hipStream_t stream) {
  const float* query = (const float*)d_in[0];
  const int* mask = (const int*)d_in[1];
  const float* Wq = (const float*)d_in[2];
  const float* Wk = (const float*)d_in[3];
  const float* Wv = (const float*)d_in[4];
  const float* Wo = (const float*)d_in[5];
  const float* bo = (const float*)d_in[6];
  float* out = (float*)d_out;

  char* ws = (char*)d_ws;
  const size_t MB = 1024 * 1024;
  unsigned short* qbf = (unsigned short*)(ws);           // 8 MB; reused as ctx
  unsigned short* wbf = (unsigned short*)(ws + 8 * MB);  // 8 MB (Wq,Wk,Wv,Wo bf16)
  unsigned short* qb = (unsigned short*)(ws + 16 * MB);  // 8 MB
  unsigned short* kb = (unsigned short*)(ws + 24 * MB);  // 8 MB
  unsigned short* vt = (unsigned short*)(ws + 32 * MB);  // 8 MB
  unsigned long long* mb = (unsigned long long*)(ws + 40 * MB);  // 1 MB
  unsigned short* ctx = qbf;

  prep_kernel<<<32768 + 4096, 256, 0, stream>>>(query, Wq, Wk, Wv, Wo, mask,
                                                qbf, wbf, mb);

  // Q scaled by 1/sqrt(dh) * log2(e): softmax in exp2 domain
  gemm_qkv<<<dim3(3072 / 128, 4096 / 128), 256, 0, stream>>>(
      qbf, wbf, qb, kb, vt, 0.18033688f);

  attn_kernel<<<dim3(NH, S_LEN / 128, 2), 256, 0, stream>>>(qb, kb, vt, mb,
                                                            ctx);

  gemm_out<<<dim3(1024 / 64, 4096 / 128), 256, 0, stream>>>(
      ctx, wbf + 3 * 1048576, out, bo);
}